// Round 27
// baseline (32.221 us; speedup 1.0000x reference)
//
#include <hip/hip_runtime.h>

// SplineConv as skinny-K GEMM: out[n,oi] = sum_k W[n,k] * CT[k,oi].
// M=32768 points, N=1024 channels, K=64. f16 MFMA 16x16x32, f32 acc.
//
// Round-27 = round-23 (31.6us, best) with the PREP kernel restructured:
// one thread per POINT (128 blocks) instead of one thread per 16B record
// (1024 blocks): span_weights computed once per point (was 8x redundant),
// 41K threads instead of 270K, 160 blocks total instead of 1056. Each thread
// emits its point's 8 fragment records (8 x 16B stores; wave-adjacent prow
// -> 256B segments per (st,g)). Wp layout byte-identical to R13-R26
// (record (tile,st,lane) = point tile*16+(lane&15), k=st*32+(lane>>4)*8+j).
// Main kernel BYTE-IDENTICAL to R23:
//  - T1 XCD swizzle (+8% confirmed), plain write-back stores (+7% confirmed),
//    wave-private XOR transpose (no barriers), 4 x 256B full-line stores,
//    Wp prefetch-1.

#define NPTS   32768
#define DIM    1024
#define MT     (NPTS / 16)        // 2048 point-tiles
#define WELEM  (MT * 2 * 64 * 8)  // W_perm f16 elements (4 MiB)

typedef _Float16 f16x8 __attribute__((ext_vector_type(8)));
typedef float    f32x4 __attribute__((ext_vector_type(4)));

__device__ __forceinline__ float safe_div(float n, float d) {
    return (d == 0.0f) ? n : (n / d);
}

__device__ __forceinline__ void span_weights(float v, const float* __restrict__ T,
                                             int& k, float& w0, float& w1, float& w2) {
    float t3 = T[3], t4 = T[4], t5 = T[5], t6 = T[6];
    k = 2 + (v >= t3) + (v >= t4) + (v >= t5) + (v >= t6);
    float Tm1 = T[k - 1], T0 = T[k], Tp1 = T[k + 1], Tp2 = T[k + 2];
    float a10 = safe_div(v - Tm1, Tp1 - Tm1);
    float a11 = safe_div(v - T0,  Tp2 - T0);
    float a21 = safe_div(v - T0,  Tp1 - T0);
    w0 = (1.0f - a21) * (1.0f - a10);
    w1 = (1.0f - a21) * a10 + a21 * (1.0f - a11);
    w2 = a21 * a11;
}

__global__ __launch_bounds__(256) void prep_kernel(
    const float* __restrict__ xy,
    const float* __restrict__ Tx,
    const float* __restrict__ Ty,
    const float* __restrict__ C,
    _Float16* __restrict__ Wp,
    _Float16* __restrict__ Cp)
{
    const int b = blockIdx.x;
    const int t = threadIdx.x;
    if (b < NPTS / 256) {
        // ---- W_perm: ONE THREAD PER POINT: span_weights once, emit 8 records.
        const int n    = b * 256 + t;
        const int tile = n >> 4;
        const int prow = n & 15;

        const float2 pt = ((const float2*)xy)[n];
        int kx, ky;
        float wx0, wx1, wx2, wy0, wy1, wy2;
        span_weights(pt.x, Tx, kx, wx0, wx1, wx2);
        span_weights(pt.y, Ty, ky, wy0, wy1, wy2);
        const int off = (kx - 2) * 7 + (ky - 2);

        _Float16* base = Wp + (size_t)tile * (2 * 64 * 8);
#pragma unroll
        for (int st = 0; st < 2; ++st)
#pragma unroll
            for (int g = 0; g < 4; ++g) {
                f16x8 frag;
#pragma unroll
                for (int j = 0; j < 8; ++j) {
                    const int k   = st * 32 + g * 8 + j;
                    const int rel = k - off;
                    const float va = (rel >= 14) ? wx2 : ((rel >= 7) ? wx1 : wx0);
                    const int   bb = rel - ((rel >= 14) ? 14 : ((rel >= 7) ? 7 : 0));
                    const float vb = (bb == 0) ? wy0 : ((bb == 1) ? wy1 : wy2);
                    const bool valid = (rel >= 0) && (rel <= 16) && (bb >= 0) && (bb <= 2);
                    frag[j] = (_Float16)(valid ? va * vb : 0.0f);
                }
                *(f16x8*)(base + ((size_t)st * 64 + g * 16 + prow) * 8) = frag;
            }
    } else {
        // ---- C_perm: C[ch][k] in A-fragment order (row=ch, k-grouped) ----
        const int id    = (b - NPTS / 256) * 256 + t;   // 0 .. 8191
        const int lane  = id & 63;
        const int step  = (id >> 6) & 1;
        const int ctile = id >> 7;
        const int ch    = ctile * 16 + (lane & 15);
        const int g     = lane >> 4;

        f16x8 frag;
#pragma unroll
        for (int j = 0; j < 8; ++j) {
            const int k = step * 32 + g * 8 + j;
            frag[j] = (_Float16)((k < 49) ? C[(size_t)ch * 49 + k] : 0.0f);
        }
        *(f16x8*)(Cp + (size_t)id * 8) = frag;
    }
}

__global__ __launch_bounds__(256, 4) void spline_mfma_kernel(
    const _Float16* __restrict__ Wp,
    const _Float16* __restrict__ Cp,
    float* __restrict__ out)
{
    __shared__ float lds[4 * 1024];            // 4 KiB per wave, private

    const int t    = threadIdx.x;
    const int lane = t & 63;
    const int w    = t >> 6;                   // wave 0..3

    // --- T1 XCD swizzle (confirmed +8%): contiguous output per XCD. ---
    const int bid    = blockIdx.x;
    const int swz    = ((bid & 7) << 7) | (bid >> 3);
    const int chgrp  = swz & 3;                // 256-channel group
    const int pchunk = swz >> 2;               // 8 point-tile chunk (128 points)

    float* const wbuf = lds + w * 1024;        // this wave's region

    // A-fragments: this wave's 4 channel-tiles x 2 k-steps (register-resident;
    // Cp is 128 KiB -> L2-hot for every block).
    f16x8 af[4][2];
#pragma unroll
    for (int ct = 0; ct < 4; ++ct)
#pragma unroll
        for (int st = 0; st < 2; ++st) {
            const int ctg = chgrp * 16 + w * 4 + ct;
            af[ct][st] = *(const f16x8*)(Cp + ((size_t)(ctg * 2 + st) * 64 + lane) * 8);
        }

    const int p  = lane & 15;                  // D col = point within tile
    const int h  = lane >> 4;                  // D row group
    const int cb = lane & 15;                  // read-back granule index

    // Prefetch first tile's B-fragments.
    const int ptile0 = pchunk * 8;
    f16x8 nb0 = *(const f16x8*)(Wp + ((size_t)(ptile0 * 2 + 0) * 64 + lane) * 8);
    f16x8 nb1 = *(const f16x8*)(Wp + ((size_t)(ptile0 * 2 + 1) * 64 + lane) * 8);

#pragma unroll
    for (int pt = 0; pt < 8; ++pt) {
        const int ptile = pchunk * 8 + pt;
        const f16x8 b0 = nb0;
        const f16x8 b1 = nb1;
        if (pt + 1 < 8) {   // issue next tile's loads BEFORE this tile's stores
            nb0 = *(const f16x8*)(Wp + ((size_t)((ptile + 1) * 2 + 0) * 64 + lane) * 8);
            nb1 = *(const f16x8*)(Wp + ((size_t)((ptile + 1) * 2 + 1) * 64 + lane) * 8);
        }

        f32x4 acc[4];
#pragma unroll
        for (int ct = 0; ct < 4; ++ct) {
            f32x4 z; z[0] = 0.0f; z[1] = 0.0f; z[2] = 0.0f; z[3] = 0.0f;
            acc[ct] = __builtin_amdgcn_mfma_f32_16x16x32_f16(af[ct][0], b0, z, 0, 0, 0);
        }
#pragma unroll
        for (int ct = 0; ct < 4; ++ct)
            acc[ct] = __builtin_amdgcn_mfma_f32_16x16x32_f16(af[ct][1], b1, acc[ct], 0, 0, 0);

        // --- Wave-private LDS transpose (no barrier). Write: point p, granule
        // g16 = ct*4+h (channels g16*4..+3 of this wave's 64), XOR-swizzled. ---
#pragma unroll
        for (int ct = 0; ct < 4; ++ct) {
            const int g16 = ct * 4 + h;
            const int col = (g16 & 8) | ((g16 ^ p) & 7);
            *(f32x4*)(wbuf + p * 64 + (col << 2)) = acc[ct];
        }

        // --- Read back + store: instr gg covers points gg*4..gg*4+3, each as
        // 16 lanes x 16B = 256B contiguous (2 full 128B lines). Plain
        // write-back stores (L3 absorbs the contiguous per-XCD stream). ---
#pragma unroll
        for (int gg = 0; gg < 4; ++gg) {
            const int pr  = gg * 4 + h;
            const int col = (cb & 8) | ((cb ^ pr) & 7);
            f32x4 v = *(const f32x4*)(wbuf + pr * 64 + (col << 2));
            float* dst = out + (size_t)(ptile * 16 + pr) * DIM
                             + chgrp * 256 + w * 64 + cb * 4;
            *(f32x4*)dst = v;
        }
    }
}

extern "C" void kernel_launch(void* const* d_in, const int* in_sizes, int n_in,
                              void* d_out, int out_size, void* d_ws, size_t ws_size,
                              hipStream_t stream) {
    const float* xy = (const float*)d_in[0];
    const float* Tx = (const float*)d_in[1];
    const float* Ty = (const float*)d_in[2];
    const float* C  = (const float*)d_in[3];
    float* out = (float*)d_out;

    _Float16* Wp = (_Float16*)d_ws;            // 4 MiB
    _Float16* Cp = Wp + WELEM;                 // 128 KiB

    prep_kernel<<<NPTS / 256 + 32, 256, 0, stream>>>(xy, Tx, Ty, C, Wp, Cp);
    spline_mfma_kernel<<<4 * (MT / 8), 256, 0, stream>>>(Wp, Cp, out);
}

// Round 28
// 32.084 us; speedup vs baseline: 1.0043x; 1.0043x over previous
//
#include <hip/hip_runtime.h>

// SplineConv as skinny-K GEMM: out[n,oi] = sum_k W[n,k] * CT[k,oi].
// M=32768 points, N=1024 channels, K=64. f16 MFMA 16x16x32, f32 acc.
//
// Round-28 = round-23 (31.6us, best) with the OCCUPANCY axis tested: halve
// per-wave footprint (2 ch-tiles/wave, af[2][2]+acc[2] ~55-60 VGPR) and
// declare __launch_bounds__(256, 8) -> target 32 waves/CU (the 6.7 TB/s fill
// kernel's occupancy) vs R23's 16. Store BW is queue-depth-limited per wave;
// doubling resident waves doubles outstanding stores. Grid 2048 (=8 XCD x 256,
// bijective swizzle). Wave-private transpose scaled to 2 KiB/wave (8/bank
// balanced both directions); 2 store instrs/iter, 8 x 128B full lines each.
//  - T1 XCD swizzle (+8% confirmed), plain write-back (+7% confirmed),
//    Wp prefetch-1, no barriers - all carried from R23.
// prep_kernel identical to R23 (verified, absmax 1.95e-3).

#define NPTS   32768
#define DIM    1024
#define MT     (NPTS / 16)        // 2048 point-tiles
#define WELEM  (MT * 2 * 64 * 8)  // W_perm f16 elements (4 MiB)

typedef _Float16 f16x8 __attribute__((ext_vector_type(8)));
typedef float    f32x4 __attribute__((ext_vector_type(4)));

__device__ __forceinline__ float safe_div(float n, float d) {
    return (d == 0.0f) ? n : (n / d);
}

__device__ __forceinline__ void span_weights(float v, const float* __restrict__ T,
                                             int& k, float& w0, float& w1, float& w2) {
    float t3 = T[3], t4 = T[4], t5 = T[5], t6 = T[6];
    k = 2 + (v >= t3) + (v >= t4) + (v >= t5) + (v >= t6);
    float Tm1 = T[k - 1], T0 = T[k], Tp1 = T[k + 1], Tp2 = T[k + 2];
    float a10 = safe_div(v - Tm1, Tp1 - Tm1);
    float a11 = safe_div(v - T0,  Tp2 - T0);
    float a21 = safe_div(v - T0,  Tp1 - T0);
    w0 = (1.0f - a21) * (1.0f - a10);
    w1 = (1.0f - a21) * a10 + a21 * (1.0f - a11);
    w2 = a21 * a11;
}

__global__ __launch_bounds__(256) void prep_kernel(
    const float* __restrict__ xy,
    const float* __restrict__ Tx,
    const float* __restrict__ Ty,
    const float* __restrict__ C,
    _Float16* __restrict__ Wp,
    _Float16* __restrict__ Cp)
{
    const int b = blockIdx.x;
    const int t = threadIdx.x;
    if (b < MT / 2) {
        // ---- W_perm: one thread per (point-tile, k-step, lane) 16B record ----
        const int id   = b * 256 + t;          // 0 .. 262143
        const int lane = id & 63;
        const int step = (id >> 6) & 1;
        const int tile = id >> 7;
        const int n    = tile * 16 + (lane & 15);   // B col = lane%16
        const int g    = lane >> 4;                  // k-group

        const float2 pt = ((const float2*)xy)[n];
        int kx, ky;
        float wx0, wx1, wx2, wy0, wy1, wy2;
        span_weights(pt.x, Tx, kx, wx0, wx1, wx2);
        span_weights(pt.y, Ty, ky, wy0, wy1, wy2);
        const int off = (kx - 2) * 7 + (ky - 2);

        f16x8 frag;
#pragma unroll
        for (int j = 0; j < 8; ++j) {
            const int k   = step * 32 + g * 8 + j;
            const int rel = k - off;
            const float va = (rel >= 14) ? wx2 : ((rel >= 7) ? wx1 : wx0);
            const int   bb = rel - ((rel >= 14) ? 14 : ((rel >= 7) ? 7 : 0));
            const float vb = (bb == 0) ? wy0 : ((bb == 1) ? wy1 : wy2);
            const bool valid = (rel >= 0) && (rel <= 16) && (bb >= 0) && (bb <= 2);
            frag[j] = (_Float16)(valid ? va * vb : 0.0f);
        }
        *(f16x8*)(Wp + (size_t)id * 8) = frag;
    } else if (b < MT / 2 + 32) {
        // ---- C_perm: C[ch][k] in A-fragment order (row=ch, k-grouped) ----
        const int id    = (b - MT / 2) * 256 + t;   // 0 .. 8191
        const int lane  = id & 63;
        const int step  = (id >> 6) & 1;
        const int ctile = id >> 7;
        const int ch    = ctile * 16 + (lane & 15); // A row = lane%16
        const int g     = lane >> 4;

        f16x8 frag;
#pragma unroll
        for (int j = 0; j < 8; ++j) {
            const int k = step * 32 + g * 8 + j;
            frag[j] = (_Float16)((k < 49) ? C[(size_t)ch * 49 + k] : 0.0f);
        }
        *(f16x8*)(Cp + (size_t)id * 8) = frag;
    }
}

__global__ __launch_bounds__(256, 8) void spline_mfma_kernel(
    const _Float16* __restrict__ Wp,
    const _Float16* __restrict__ Cp,
    float* __restrict__ out)
{
    __shared__ float lds[4 * 512];             // 2 KiB per wave, private

    const int t    = threadIdx.x;
    const int lane = t & 63;
    const int w    = t >> 6;                   // wave 0..3

    // --- T1 XCD swizzle: 2048 blocks = 8 XCDs x 256, bijective. ---
    const int bid    = blockIdx.x;
    const int swz    = ((bid & 7) << 8) | (bid >> 3);
    const int chgrp  = swz & 7;                // 128-channel group
    const int pchunk = swz >> 3;               // 8 point-tile chunk (128 points)

    float* const wbuf = lds + w * 512;         // this wave's 2 KiB region

    // A-fragments: this wave's 2 channel-tiles x 2 k-steps (16 VGPR;
    // Cp is 128 KiB -> L2-hot for every block).
    f16x8 af[2][2];
#pragma unroll
    for (int ct = 0; ct < 2; ++ct)
#pragma unroll
        for (int st = 0; st < 2; ++st) {
            const int ctg = chgrp * 8 + w * 2 + ct;
            af[ct][st] = *(const f16x8*)(Cp + ((size_t)(ctg * 2 + st) * 64 + lane) * 8);
        }

    const int p = lane & 15;                   // D col = point within tile
    const int h = lane >> 4;                   // D row group

    // Prefetch first tile's B-fragments.
    const int ptile0 = pchunk * 8;
    f16x8 nb0 = *(const f16x8*)(Wp + ((size_t)(ptile0 * 2 + 0) * 64 + lane) * 8);
    f16x8 nb1 = *(const f16x8*)(Wp + ((size_t)(ptile0 * 2 + 1) * 64 + lane) * 8);

#pragma unroll
    for (int pt = 0; pt < 8; ++pt) {
        const int ptile = pchunk * 8 + pt;
        const f16x8 b0 = nb0;
        const f16x8 b1 = nb1;
        if (pt + 1 < 8) {   // issue next tile's loads BEFORE this tile's stores
            nb0 = *(const f16x8*)(Wp + ((size_t)((ptile + 1) * 2 + 0) * 64 + lane) * 8);
            nb1 = *(const f16x8*)(Wp + ((size_t)((ptile + 1) * 2 + 1) * 64 + lane) * 8);
        }

        f32x4 acc[2];
#pragma unroll
        for (int ct = 0; ct < 2; ++ct) {
            f32x4 z; z[0] = 0.0f; z[1] = 0.0f; z[2] = 0.0f; z[3] = 0.0f;
            acc[ct] = __builtin_amdgcn_mfma_f32_16x16x32_f16(af[ct][0], b0, z, 0, 0, 0);
        }
#pragma unroll
        for (int ct = 0; ct < 2; ++ct)
            acc[ct] = __builtin_amdgcn_mfma_f32_16x16x32_f16(af[ct][1], b1, acc[ct], 0, 0, 0);

        // --- Wave-private LDS transpose (no barrier). Lane (p,h), granule
        // g = ct*4+h of 8 granules (32 ch = 8 x 4ch). XOR swizzle keeps the
        // 8/bank balanced floor in both directions. ---
#pragma unroll
        for (int ct = 0; ct < 2; ++ct) {
            const int col = (ct * 16 + h * 4) ^ ((p & 7) << 2);
            *(f32x4*)(wbuf + p * 32 + col) = acc[ct];
        }

        // --- Read back + store: instr s covers points s*8..s*8+7, each as
        // 8 lanes x 16B = 128B contiguous (1 full line per point). ---
#pragma unroll
        for (int s = 0; s < 2; ++s) {
            const int pr = s * 8 + (lane >> 3);
            const int cg = lane & 7;
            const int col = (cg * 4) ^ ((pr & 7) << 2);
            f32x4 v = *(const f32x4*)(wbuf + pr * 32 + col);
            float* dst = out + (size_t)(ptile * 16 + pr) * DIM
                             + chgrp * 128 + w * 32 + cg * 4;
            *(f32x4*)dst = v;
        }
    }
}

extern "C" void kernel_launch(void* const* d_in, const int* in_sizes, int n_in,
                              void* d_out, int out_size, void* d_ws, size_t ws_size,
                              hipStream_t stream) {
    const float* xy = (const float*)d_in[0];
    const float* Tx = (const float*)d_in[1];
    const float* Ty = (const float*)d_in[2];
    const float* C  = (const float*)d_in[3];
    float* out = (float*)d_out;

    _Float16* Wp = (_Float16*)d_ws;            // 4 MiB
    _Float16* Cp = Wp + WELEM;                 // 128 KiB

    prep_kernel<<<MT / 2 + 32, 256, 0, stream>>>(xy, Tx, Ty, C, Wp, Cp);
    spline_mfma_kernel<<<8 * (MT / 8), 256, 0, stream>>>(Wp, Cp, out);
}